// Round 4
// baseline (61.442 us; speedup 1.0000x reference)
//
#include <hip/hip_runtime.h>
#include <math.h>

// Causal depthwise conv1d (K=4) + SiLU.
// x: (B,T,C) f32, weight: (C,K) f32, bias: (C,) f32 -> out: (B,T,C) f32
// y[b,t,c] = bias[c] + sum_k w[c,k] * x[b, t-K+1+k, c];  out = silu(y)

constexpr int KSZ   = 4;
constexpr int TT    = 16;   // time steps per thread
constexpr int BLOCK = 256;  // threads per block (multiple of wave=64)

__device__ __forceinline__ float silu_f(float y) {
    return y * __builtin_amdgcn_rcpf(1.0f + __expf(-y));
}

// __launch_bounds__(256, 4): 4 waves/EU = 16 waves/CU -> allocator may use up
// to ~128 VGPRs, so the 19-deep float4 preload stays live (19 loads in flight
// per wave) instead of being re-interleaved down to ~6.
__global__ __launch_bounds__(BLOCK, 4) void dwconv_silu_kernel(
    const float* __restrict__ x, const float* __restrict__ w,
    const float* __restrict__ bias, float* __restrict__ out,
    int T, int C) {

    const int b  = blockIdx.z;
    const int t0 = blockIdx.y * TT;
    const int c4 = (blockIdx.x * BLOCK + threadIdx.x) * 4;  // 4 channels/thread
    if (c4 >= C) return;

    const float4 w0 = *reinterpret_cast<const float4*>(w + (size_t)(c4 + 0) * KSZ);
    const float4 w1 = *reinterpret_cast<const float4*>(w + (size_t)(c4 + 1) * KSZ);
    const float4 w2 = *reinterpret_cast<const float4*>(w + (size_t)(c4 + 2) * KSZ);
    const float4 w3 = *reinterpret_cast<const float4*>(w + (size_t)(c4 + 3) * KSZ);
    const float4 bv = *reinterpret_cast<const float4*>(bias + c4);

    const float* xb = x   + (size_t)b * T * C + c4;
    float*       ob = out + (size_t)b * T * C + c4;

    const float4 zero = make_float4(0.f, 0.f, 0.f, 0.f);

    if (t0 + TT <= T) {
        // -------- fast path: preload the whole tile (TT+3 float4) --------
        float4 xs[TT + 3];
        xs[0] = (t0 - 3 >= 0) ? *reinterpret_cast<const float4*>(xb + (size_t)(t0 - 3) * C) : zero;
        xs[1] = (t0 - 2 >= 0) ? *reinterpret_cast<const float4*>(xb + (size_t)(t0 - 2) * C) : zero;
        xs[2] = (t0 - 1 >= 0) ? *reinterpret_cast<const float4*>(xb + (size_t)(t0 - 1) * C) : zero;
#pragma unroll
        for (int tt = 0; tt < TT; ++tt)
            xs[tt + 3] = *reinterpret_cast<const float4*>(xb + (size_t)(t0 + tt) * C);

#pragma unroll
        for (int tt = 0; tt < TT; ++tt) {
            const float4 a  = xs[tt + 0];
            const float4 bq = xs[tt + 1];
            const float4 cq = xs[tt + 2];
            const float4 d  = xs[tt + 3];
            float4 y;
            y.x = bv.x + w0.x * a.x + w0.y * bq.x + w0.z * cq.x + w0.w * d.x;
            y.y = bv.y + w1.x * a.y + w1.y * bq.y + w1.z * cq.y + w1.w * d.y;
            y.z = bv.z + w2.x * a.z + w2.y * bq.z + w2.z * cq.z + w2.w * d.z;
            y.w = bv.w + w3.x * a.w + w3.y * bq.w + w3.z * cq.w + w3.w * d.w;
            float4 o;
            o.x = silu_f(y.x);
            o.y = silu_f(y.y);
            o.z = silu_f(y.z);
            o.w = silu_f(y.w);
            *reinterpret_cast<float4*>(ob + (size_t)(t0 + tt) * C) = o;
        }
    } else {
        // -------- tail path: guarded sliding window --------
        float4 xm3 = (t0 - 3 >= 0) ? *reinterpret_cast<const float4*>(xb + (size_t)(t0 - 3) * C) : zero;
        float4 xm2 = (t0 - 2 >= 0) ? *reinterpret_cast<const float4*>(xb + (size_t)(t0 - 2) * C) : zero;
        float4 xm1 = (t0 - 1 >= 0) ? *reinterpret_cast<const float4*>(xb + (size_t)(t0 - 1) * C) : zero;
        for (int tt = 0; tt < TT; ++tt) {
            const int t = t0 + tt;
            if (t >= T) break;
            const float4 xc = *reinterpret_cast<const float4*>(xb + (size_t)t * C);
            float4 y;
            y.x = bv.x + w0.x * xm3.x + w0.y * xm2.x + w0.z * xm1.x + w0.w * xc.x;
            y.y = bv.y + w1.x * xm3.y + w1.y * xm2.y + w1.z * xm1.y + w1.w * xc.y;
            y.z = bv.z + w2.x * xm3.z + w2.y * xm2.z + w2.z * xm1.z + w2.w * xc.z;
            y.w = bv.w + w3.x * xm3.w + w3.y * xm2.w + w3.z * xm1.w + w3.w * xc.w;
            float4 o;
            o.x = silu_f(y.x);
            o.y = silu_f(y.y);
            o.z = silu_f(y.z);
            o.w = silu_f(y.w);
            *reinterpret_cast<float4*>(ob + (size_t)t * C) = o;
            xm3 = xm2; xm2 = xm1; xm1 = xc;
        }
    }
}

extern "C" void kernel_launch(void* const* d_in, const int* in_sizes, int n_in,
                              void* d_out, int out_size, void* d_ws, size_t ws_size,
                              hipStream_t stream) {
    const float* x    = (const float*)d_in[0];
    const float* w    = (const float*)d_in[1];
    const float* bias = (const float*)d_in[2];
    float*       out  = (float*)d_out;

    const int C  = in_sizes[2];          // 2048
    const int BT = in_sizes[0] / C;      // B*T = 16384
    int T = 4096;
    if (BT % T != 0) T = BT;             // fallback: treat as single batch
    const int B = BT / T;

    dim3 block(BLOCK);
    dim3 grid((C + 4 * BLOCK - 1) / (4 * BLOCK),  // channel tiles
              (T + TT - 1) / TT,                  // time tiles
              B);                                 // batch

    dwconv_silu_kernel<<<grid, block, 0, stream>>>(x, w, bias, out, T, C);
}

// Round 6
// 49.252 us; speedup vs baseline: 1.2475x; 1.2475x over previous
//
#include <hip/hip_runtime.h>
#include <math.h>

// Causal depthwise conv1d (K=4) + SiLU.
// x: (B,T,C) f32, weight: (C,K) f32, bias: (C,) f32 -> out: (B,T,C) f32
// y[b,t,c] = bias[c] + sum_k w[c,k] * x[b, t-K+1+k, c];  out = silu(y)
//
// R6: force the 19-deep global_load queue with an empty asm-volatile that
// consumes all loaded vectors (scheduling barrier) -> max memory-level
// parallelism per wave. Plain float4 stores (nt variants inflated WRITE_SIZE
// or broke correctness).

constexpr int KSZ   = 4;
constexpr int TT    = 16;   // time steps per thread
constexpr int BLOCK = 256;  // threads per block (multiple of wave=64)

typedef float floatx4 __attribute__((ext_vector_type(4)));  // native clang vector: valid "v" asm operand

__device__ __forceinline__ float silu_f(float y) {
    return y * __builtin_amdgcn_rcpf(1.0f + __expf(-y));
}

__global__ __launch_bounds__(BLOCK) void dwconv_silu_kernel(
    const float* __restrict__ x, const float* __restrict__ w,
    const float* __restrict__ bias, float* __restrict__ out,
    int T, int C) {

    const int b  = blockIdx.z;
    const int t0 = blockIdx.y * TT;
    const int c4 = (blockIdx.x * BLOCK + threadIdx.x) * 4;  // 4 channels/thread
    if (c4 >= C) return;

    const float4 w0 = *reinterpret_cast<const float4*>(w + (size_t)(c4 + 0) * KSZ);
    const float4 w1 = *reinterpret_cast<const float4*>(w + (size_t)(c4 + 1) * KSZ);
    const float4 w2 = *reinterpret_cast<const float4*>(w + (size_t)(c4 + 2) * KSZ);
    const float4 w3 = *reinterpret_cast<const float4*>(w + (size_t)(c4 + 3) * KSZ);
    const float4 bv = *reinterpret_cast<const float4*>(bias + c4);

    const float* xb = x   + (size_t)b * T * C + c4;
    float*       ob = out + (size_t)b * T * C + c4;

    if (t0 + TT <= T) {
        // -------- fast path: preload the whole tile (TT+3 float4) --------
        floatx4 xs[TT + 3];
        const floatx4 zero4 = (floatx4){0.f, 0.f, 0.f, 0.f};
        xs[0] = (t0 - 3 >= 0) ? *reinterpret_cast<const floatx4*>(xb + (size_t)(t0 - 3) * C) : zero4;
        xs[1] = (t0 - 2 >= 0) ? *reinterpret_cast<const floatx4*>(xb + (size_t)(t0 - 2) * C) : zero4;
        xs[2] = (t0 - 1 >= 0) ? *reinterpret_cast<const floatx4*>(xb + (size_t)(t0 - 1) * C) : zero4;
#pragma unroll
        for (int tt = 0; tt < TT; ++tt)
            xs[tt + 3] = *reinterpret_cast<const floatx4*>(xb + (size_t)(t0 + tt) * C);

        // Scheduling fence: demand ALL 19 vectors here so the compiler issues
        // 19 back-to-back global_load_dwordx4 (one waitcnt), instead of
        // interleaving each load with its consumer (rule-17 liveness trick).
        asm volatile("" ::
            "v"(xs[0]),  "v"(xs[1]),  "v"(xs[2]),  "v"(xs[3]),  "v"(xs[4]),
            "v"(xs[5]),  "v"(xs[6]),  "v"(xs[7]),  "v"(xs[8]),  "v"(xs[9]),
            "v"(xs[10]), "v"(xs[11]), "v"(xs[12]), "v"(xs[13]), "v"(xs[14]),
            "v"(xs[15]), "v"(xs[16]), "v"(xs[17]), "v"(xs[18]));

#pragma unroll
        for (int tt = 0; tt < TT; ++tt) {
            const floatx4 a  = xs[tt + 0];
            const floatx4 bq = xs[tt + 1];
            const floatx4 cq = xs[tt + 2];
            const floatx4 d  = xs[tt + 3];
            float4 y;
            y.x = bv.x + w0.x * a.x + w0.y * bq.x + w0.z * cq.x + w0.w * d.x;
            y.y = bv.y + w1.x * a.y + w1.y * bq.y + w1.z * cq.y + w1.w * d.y;
            y.z = bv.z + w2.x * a.z + w2.y * bq.z + w2.z * cq.z + w2.w * d.z;
            y.w = bv.w + w3.x * a.w + w3.y * bq.w + w3.z * cq.w + w3.w * d.w;
            float4 o;
            o.x = silu_f(y.x);
            o.y = silu_f(y.y);
            o.z = silu_f(y.z);
            o.w = silu_f(y.w);
            *reinterpret_cast<float4*>(ob + (size_t)(t0 + tt) * C) = o;
        }
    } else {
        // -------- tail path: guarded sliding window --------
        const float4 zero = make_float4(0.f, 0.f, 0.f, 0.f);
        float4 xm3 = (t0 - 3 >= 0) ? *reinterpret_cast<const float4*>(xb + (size_t)(t0 - 3) * C) : zero;
        float4 xm2 = (t0 - 2 >= 0) ? *reinterpret_cast<const float4*>(xb + (size_t)(t0 - 2) * C) : zero;
        float4 xm1 = (t0 - 1 >= 0) ? *reinterpret_cast<const float4*>(xb + (size_t)(t0 - 1) * C) : zero;
        for (int tt = 0; tt < TT; ++tt) {
            const int t = t0 + tt;
            if (t >= T) break;
            const float4 xc = *reinterpret_cast<const float4*>(xb + (size_t)t * C);
            float4 y;
            y.x = bv.x + w0.x * xm3.x + w0.y * xm2.x + w0.z * xm1.x + w0.w * xc.x;
            y.y = bv.y + w1.x * xm3.y + w1.y * xm2.y + w1.z * xm1.y + w1.w * xc.y;
            y.z = bv.z + w2.x * xm3.z + w2.y * xm2.z + w2.z * xm1.z + w2.w * xc.z;
            y.w = bv.w + w3.x * xm3.w + w3.y * xm2.w + w3.z * xm1.w + w3.w * xc.w;
            float4 o;
            o.x = silu_f(y.x);
            o.y = silu_f(y.y);
            o.z = silu_f(y.z);
            o.w = silu_f(y.w);
            *reinterpret_cast<float4*>(ob + (size_t)t * C) = o;
            xm3 = xm2; xm2 = xm1; xm1 = xc;
        }
    }
}

extern "C" void kernel_launch(void* const* d_in, const int* in_sizes, int n_in,
                              void* d_out, int out_size, void* d_ws, size_t ws_size,
                              hipStream_t stream) {
    const float* x    = (const float*)d_in[0];
    const float* w    = (const float*)d_in[1];
    const float* bias = (const float*)d_in[2];
    float*       out  = (float*)d_out;

    const int C  = in_sizes[2];          // 2048
    const int BT = in_sizes[0] / C;      // B*T = 16384
    int T = 4096;
    if (BT % T != 0) T = BT;             // fallback: treat as single batch
    const int B = BT / T;

    dim3 block(BLOCK);
    dim3 grid((C + 4 * BLOCK - 1) / (4 * BLOCK),  // channel tiles
              (T + TT - 1) / TT,                  // time tiles
              B);                                 // batch

    dwconv_silu_kernel<<<grid, block, 0, stream>>>(x, w, bias, out, T, C);
}

// Round 7
// 46.191 us; speedup vs baseline: 1.3302x; 1.0663x over previous
//
#include <hip/hip_runtime.h>
#include <math.h>

// Causal depthwise conv1d (K=4) + SiLU.
// x: (B,T,C) f32, weight: (C,K) f32, bias: (C,) f32 -> out: (B,T,C) f32
// y[b,t,c] = bias[c] + sum_k w[c,k] * x[b, t-K+1+k, c];  out = silu(y)
//
// R7: TT=32 (35-row register preload). Halves block/stream count vs TT=16,
// doubles per-stream sequential span (DRAM row locality), halo redundancy
// 1.19x -> 1.09x. Occupancy drops to ~8-10 waves/CU, shown perf-neutral in
// R4/R6 (70% vs 32% occ both 49-51 us).

constexpr int KSZ   = 4;
constexpr int TT    = 32;   // time steps per thread
constexpr int BLOCK = 256;  // threads per block (multiple of wave=64)

typedef float floatx4 __attribute__((ext_vector_type(4)));

__device__ __forceinline__ float silu_f(float y) {
    return y * __builtin_amdgcn_rcpf(1.0f + __expf(-y));
}

__global__ __launch_bounds__(BLOCK) void dwconv_silu_kernel(
    const float* __restrict__ x, const float* __restrict__ w,
    const float* __restrict__ bias, float* __restrict__ out,
    int T, int C) {

    const int b  = blockIdx.z;
    const int t0 = blockIdx.y * TT;
    const int c4 = (blockIdx.x * BLOCK + threadIdx.x) * 4;  // 4 channels/thread
    if (c4 >= C) return;

    const float4 w0 = *reinterpret_cast<const float4*>(w + (size_t)(c4 + 0) * KSZ);
    const float4 w1 = *reinterpret_cast<const float4*>(w + (size_t)(c4 + 1) * KSZ);
    const float4 w2 = *reinterpret_cast<const float4*>(w + (size_t)(c4 + 2) * KSZ);
    const float4 w3 = *reinterpret_cast<const float4*>(w + (size_t)(c4 + 3) * KSZ);
    const float4 bv = *reinterpret_cast<const float4*>(bias + c4);

    const float* xb = x   + (size_t)b * T * C + c4;
    float*       ob = out + (size_t)b * T * C + c4;

    if (t0 + TT <= T) {
        // -------- fast path: preload the whole tile (TT+3 float4 rows) --------
        floatx4 xs[TT + 3];
        const floatx4 zero4 = (floatx4){0.f, 0.f, 0.f, 0.f};
        xs[0] = (t0 - 3 >= 0) ? *reinterpret_cast<const floatx4*>(xb + (size_t)(t0 - 3) * C) : zero4;
        xs[1] = (t0 - 2 >= 0) ? *reinterpret_cast<const floatx4*>(xb + (size_t)(t0 - 2) * C) : zero4;
        xs[2] = (t0 - 1 >= 0) ? *reinterpret_cast<const floatx4*>(xb + (size_t)(t0 - 1) * C) : zero4;
#pragma unroll
        for (int tt = 0; tt < TT; ++tt)
            xs[tt + 3] = *reinterpret_cast<const floatx4*>(xb + (size_t)(t0 + tt) * C);

        // Keep the whole tile live here -> loads issue back-to-back (batch
        // issue, single waitcnt) instead of load/use interleave.
        asm volatile("" ::
            "v"(xs[0]),  "v"(xs[1]),  "v"(xs[2]),  "v"(xs[3]),  "v"(xs[4]),
            "v"(xs[5]),  "v"(xs[6]),  "v"(xs[7]),  "v"(xs[8]),  "v"(xs[9]),
            "v"(xs[10]), "v"(xs[11]));
        asm volatile("" ::
            "v"(xs[12]), "v"(xs[13]), "v"(xs[14]), "v"(xs[15]), "v"(xs[16]),
            "v"(xs[17]), "v"(xs[18]), "v"(xs[19]), "v"(xs[20]), "v"(xs[21]),
            "v"(xs[22]), "v"(xs[23]));
        asm volatile("" ::
            "v"(xs[24]), "v"(xs[25]), "v"(xs[26]), "v"(xs[27]), "v"(xs[28]),
            "v"(xs[29]), "v"(xs[30]), "v"(xs[31]), "v"(xs[32]), "v"(xs[33]),
            "v"(xs[34]));

#pragma unroll
        for (int tt = 0; tt < TT; ++tt) {
            const floatx4 a  = xs[tt + 0];
            const floatx4 bq = xs[tt + 1];
            const floatx4 cq = xs[tt + 2];
            const floatx4 d  = xs[tt + 3];
            float4 y;
            y.x = bv.x + w0.x * a.x + w0.y * bq.x + w0.z * cq.x + w0.w * d.x;
            y.y = bv.y + w1.x * a.y + w1.y * bq.y + w1.z * cq.y + w1.w * d.y;
            y.z = bv.z + w2.x * a.z + w2.y * bq.z + w2.z * cq.z + w2.w * d.z;
            y.w = bv.w + w3.x * a.w + w3.y * bq.w + w3.z * cq.w + w3.w * d.w;
            float4 o;
            o.x = silu_f(y.x);
            o.y = silu_f(y.y);
            o.z = silu_f(y.z);
            o.w = silu_f(y.w);
            *reinterpret_cast<float4*>(ob + (size_t)(t0 + tt) * C) = o;
        }
    } else {
        // -------- tail path: guarded sliding window --------
        const float4 zero = make_float4(0.f, 0.f, 0.f, 0.f);
        float4 xm3 = (t0 - 3 >= 0) ? *reinterpret_cast<const float4*>(xb + (size_t)(t0 - 3) * C) : zero;
        float4 xm2 = (t0 - 2 >= 0) ? *reinterpret_cast<const float4*>(xb + (size_t)(t0 - 2) * C) : zero;
        float4 xm1 = (t0 - 1 >= 0) ? *reinterpret_cast<const float4*>(xb + (size_t)(t0 - 1) * C) : zero;
        for (int tt = 0; tt < TT; ++tt) {
            const int t = t0 + tt;
            if (t >= T) break;
            const float4 xc = *reinterpret_cast<const float4*>(xb + (size_t)t * C);
            float4 y;
            y.x = bv.x + w0.x * xm3.x + w0.y * xm2.x + w0.z * xm1.x + w0.w * xc.x;
            y.y = bv.y + w1.x * xm3.y + w1.y * xm2.y + w1.z * xm1.y + w1.w * xc.y;
            y.z = bv.z + w2.x * xm3.z + w2.y * xm2.z + w2.z * xm1.z + w2.w * xc.z;
            y.w = bv.w + w3.x * xm3.w + w3.y * xm2.w + w3.z * xm1.w + w3.w * xc.w;
            float4 o;
            o.x = silu_f(y.x);
            o.y = silu_f(y.y);
            o.z = silu_f(y.z);
            o.w = silu_f(y.w);
            *reinterpret_cast<float4*>(ob + (size_t)t * C) = o;
            xm3 = xm2; xm2 = xm1; xm1 = xc;
        }
    }
}

extern "C" void kernel_launch(void* const* d_in, const int* in_sizes, int n_in,
                              void* d_out, int out_size, void* d_ws, size_t ws_size,
                              hipStream_t stream) {
    const float* x    = (const float*)d_in[0];
    const float* w    = (const float*)d_in[1];
    const float* bias = (const float*)d_in[2];
    float*       out  = (float*)d_out;

    const int C  = in_sizes[2];          // 2048
    const int BT = in_sizes[0] / C;      // B*T = 16384
    int T = 4096;
    if (BT % T != 0) T = BT;             // fallback: treat as single batch
    const int B = BT / T;

    dim3 block(BLOCK);
    dim3 grid((C + 4 * BLOCK - 1) / (4 * BLOCK),  // channel tiles (2)
              (T + TT - 1) / TT,                  // time tiles (128)
              B);                                 // batch (4)

    dwconv_silu_kernel<<<grid, block, 0, stream>>>(x, w, bias, out, T, C);
}